// Round 2
// baseline (1950.958 us; speedup 1.0000x reference)
//
#include <hip/hip_runtime.h>
#include <math.h>

#define NBATCH 4096
#define SS 512
#define EE 64
#define MM 16
#define HH 32
#define OUTD 64
#define NSTEPS 5

__device__ __forceinline__ float fast_sigmoid(float x) {
    return 1.0f / (1.0f + __expf(-x));
}
__device__ __forceinline__ float fast_tanh(float x) {
    // tanh(x) = 1 - 2/(exp(2x)+1)
    return 1.0f - 2.0f / (__expf(2.0f * x) + 1.0f);
}

// Reading-block MLP for one row, memories returned in registers.
//
// Register-pressure discipline (the whole game on this kernel):
//  - x is streamed in 16-float chunks: peak live = xh[16] + h1[32] + few ≈ 55
//    VGPRs, far under the 128-VGPR budget of __launch_bounds__(256,4), so the
//    allocator cannot spill (previous versions had 640 B/thread of scratch
//    traffic = 669 MB of WRITE_SIZE).
//  - every loop is fully unrolled so every array index is a compile-time
//    constant (dynamic indexing demotes arrays to scratch).
//  - weight addresses are wave-uniform (base pointer + constant offsets) so
//    they ride the scalar (SMEM->SGPR) path: zero VALU, zero LDS.
//  - two partial accumulators per output break the serial FMA chain.
__device__ __forceinline__ void read_mlp_row(
    const float* __restrict__ xrow,
    const float* __restrict__ r_w1, const float* __restrict__ r_b1,
    const float* __restrict__ r_w2, const float* __restrict__ r_b2,
    const float* __restrict__ r_w3, const float* __restrict__ r_b3,
    float (&mout)[MM])
{
    float h1[HH];
    #pragma unroll
    for (int j = 0; j < HH; ++j) h1[j] = r_b1[j];

    #pragma unroll
    for (int kc = 0; kc < 4; ++kc) {
        float xh[16];
        const float4* xp = reinterpret_cast<const float4*>(xrow + kc * 16);
        #pragma unroll
        for (int i = 0; i < 4; ++i) {
            const float4 v = xp[i];
            xh[4*i+0] = v.x; xh[4*i+1] = v.y; xh[4*i+2] = v.z; xh[4*i+3] = v.w;
        }
        #pragma unroll
        for (int j = 0; j < HH; ++j) {
            const float* w = r_w1 + j * EE + kc * 16;   // uniform -> s_load
            float a0 = 0.0f, a1 = 0.0f;
            #pragma unroll
            for (int k = 0; k < 16; k += 2) {
                a0 = fmaf(xh[k],     w[k],     a0);
                a1 = fmaf(xh[k + 1], w[k + 1], a1);
            }
            h1[j] += a0 + a1;
        }
    }
    #pragma unroll
    for (int j = 0; j < HH; ++j) h1[j] = fmaxf(h1[j], 0.0f);

    float h2[HH];
    #pragma unroll
    for (int j = 0; j < HH; ++j) {
        const float* w = r_w2 + j * HH;                 // uniform -> s_load
        float a0 = r_b2[j], a1 = 0.0f;
        #pragma unroll
        for (int k = 0; k < HH; k += 2) {
            a0 = fmaf(h1[k],     w[k],     a0);
            a1 = fmaf(h1[k + 1], w[k + 1], a1);
        }
        h2[j] = fmaxf(a0 + a1, 0.0f);
    }
    #pragma unroll
    for (int d = 0; d < MM; ++d) {
        const float* w = r_w3 + d * HH;                 // uniform -> s_load
        float a0 = r_b3[d], a1 = 0.0f;
        #pragma unroll
        for (int k = 0; k < HH; k += 2) {
            a0 = fmaf(h2[k],     w[k],     a0);
            a1 = fmaf(h2[k + 1], w[k + 1], a1);
        }
        mout[d] = a0 + a1;
    }
}

extern "C" __global__ void __launch_bounds__(256, 4)
rpe_fused(const float* __restrict__ input,
          const int* __restrict__ lengths,
          const float* __restrict__ r_w1, const float* __restrict__ r_b1,
          const float* __restrict__ r_w2, const float* __restrict__ r_b2,
          const float* __restrict__ r_w3, const float* __restrict__ r_b3,
          const float* __restrict__ lstm_whh,
          const float* __restrict__ lstm_bih, const float* __restrict__ lstm_bhh,
          const float* __restrict__ proj_w, const float* __restrict__ proj_b,
          const float* __restrict__ w_w1, const float* __restrict__ w_b1,
          const float* __restrict__ w_w2, const float* __restrict__ w_b2,
          const float* __restrict__ w_w3, const float* __restrict__ w_b3,
          const float* __restrict__ empty_vec,
          float* __restrict__ out)
{
    // Phase-2 state only: ~1.5 KB LDS.
    __shared__ float s_qstar[2 * MM];
    __shared__ float s_c[HH];
    __shared__ float s_h[HH];
    __shared__ float s_gates[4 * HH];
    __shared__ float s_q[MM];
    __shared__ float s_wmax[4];
    __shared__ float s_wsum[4];
    __shared__ float s_rpart[4 * MM];
    __shared__ float s_o1[HH];
    __shared__ float s_o2[HH];

    const int b    = blockIdx.x;
    const int tid  = threadIdx.x;
    const int lane = tid & 63;
    const int wid  = tid >> 6;

    const int len      = lengths[b];
    const int safe_len = len > 0 ? len : 1;

    if (tid < HH) { s_qstar[tid] = 0.0f; s_c[tid] = 0.0f; }

    // ---------------- Phase 1: memories, kept in registers ----------------
    // Row->thread mapping matches phase-2 attention (s1=tid, s2=tid+256), so
    // memory vectors never round-trip through LDS.
    float m1[MM], m2[MM];
    read_mlp_row(input + ((size_t)b * SS + tid) * EE,
                 r_w1, r_b1, r_w2, r_b2, r_w3, r_b3, m1);
    read_mlp_row(input + ((size_t)b * SS + tid + 256) * EE,
                 r_w1, r_b1, r_w2, r_b2, r_w3, r_b3, m2);
    __syncthreads();   // covers the s_qstar/s_c init

    // ---------------- Phase 2: 5 process steps ----------------
    for (int step = 0; step < NSTEPS; ++step) {
        // gates = q_star @ whh.T + bih + bhh (zero input => no wih term)
        if (tid < 4 * HH) {
            float acc = lstm_bih[tid] + lstm_bhh[tid];
            #pragma unroll
            for (int k = 0; k < HH; ++k)
                acc = fmaf(lstm_whh[tid * HH + k], s_qstar[k], acc);
            s_gates[tid] = acc;
        }
        __syncthreads();
        if (tid < HH) {
            const float ig = fast_sigmoid(s_gates[tid]);
            const float fg = fast_sigmoid(s_gates[HH + tid]);
            const float gg = fast_tanh(s_gates[2 * HH + tid]);
            const float og = fast_sigmoid(s_gates[3 * HH + tid]);
            const float c  = fg * s_c[tid] + ig * gg;
            s_c[tid] = c;
            s_h[tid] = og * fast_tanh(c);
        }
        __syncthreads();
        // q = h @ proj_w.T + proj_b ; q_star[0:16] = q
        if (tid < MM) {
            float acc = proj_b[tid];
            #pragma unroll
            for (int k = 0; k < HH; ++k)
                acc = fmaf(proj_w[tid * HH + k], s_h[k], acc);
            s_q[tid] = acc;
            s_qstar[tid] = acc;
        }
        __syncthreads();

        // attention on register-resident memories
        float qreg[MM];
        #pragma unroll
        for (int d = 0; d < MM; ++d) qreg[d] = s_q[d];  // broadcast reads

        float e1 = 0.0f, e2 = 0.0f;
        #pragma unroll
        for (int d = 0; d < MM; ++d) {
            e1 = fmaf(m1[d], qreg[d], e1);
            e2 = fmaf(m2[d], qreg[d], e2);
        }
        if (tid       >= safe_len) e1 = -1e30f;
        if (tid + 256 >= safe_len) e2 = -1e30f;

        float mv = fmaxf(e1, e2);
        #pragma unroll
        for (int off = 32; off > 0; off >>= 1)
            mv = fmaxf(mv, __shfl_xor(mv, off, 64));
        if (lane == 0) s_wmax[wid] = mv;
        __syncthreads();
        const float maxv = fmaxf(fmaxf(s_wmax[0], s_wmax[1]),
                                 fmaxf(s_wmax[2], s_wmax[3]));

        const float p1 = __expf(e1 - maxv);   // masked -> exp(-huge) = 0
        const float p2 = __expf(e2 - maxv);
        float ds = p1 + p2;
        #pragma unroll
        for (int off = 32; off > 0; off >>= 1)
            ds += __shfl_xor(ds, off, 64);
        if (lane == 0) s_wsum[wid] = ds;

        float rv[MM];
        #pragma unroll
        for (int d = 0; d < MM; ++d) {
            float v = fmaf(p1, m1[d], p2 * m2[d]);
            #pragma unroll
            for (int off = 32; off > 0; off >>= 1)
                v += __shfl_xor(v, off, 64);
            rv[d] = v;
        }
        if (lane == 0) {
            #pragma unroll
            for (int d = 0; d < MM; ++d) s_rpart[wid * MM + d] = rv[d];
        }
        __syncthreads();
        if (tid < MM) {
            const float denom =
                s_wsum[0] + s_wsum[1] + s_wsum[2] + s_wsum[3];
            const float rval = (s_rpart[tid] + s_rpart[MM + tid] +
                                s_rpart[2 * MM + tid] + s_rpart[3 * MM + tid]) / denom;
            s_qstar[MM + tid] = rval;   // q_star[16:32] = r
        }
        __syncthreads();
    }

    // ---------------- Phase 3: write MLP + empty-set override ----------------
    if (tid < HH) {
        float acc = w_b1[tid];
        #pragma unroll
        for (int k = 0; k < 2 * MM; ++k)
            acc = fmaf(w_w1[tid * 2 * MM + k], s_qstar[k], acc);
        s_o1[tid] = fmaxf(acc, 0.0f);
    }
    __syncthreads();
    if (tid < HH) {
        float acc = w_b2[tid];
        #pragma unroll
        for (int k = 0; k < HH; ++k)
            acc = fmaf(w_w2[tid * HH + k], s_o1[k], acc);
        s_o2[tid] = fmaxf(acc, 0.0f);
    }
    __syncthreads();
    if (tid < OUTD) {
        float res;
        if (len > 0) {
            float acc = w_b3[tid];
            #pragma unroll
            for (int k = 0; k < HH; ++k)
                acc = fmaf(w_w3[tid * HH + k], s_o2[k], acc);
            res = acc;
        } else {
            res = empty_vec[tid];
        }
        out[(size_t)b * OUTD + tid] = res;
    }
}

extern "C" void kernel_launch(void* const* d_in, const int* in_sizes, int n_in,
                              void* d_out, int out_size, void* d_ws, size_t ws_size,
                              hipStream_t stream)
{
    const float* input   = (const float*)d_in[0];
    const int*   lengths = (const int*)  d_in[1];
    const float* r_w1    = (const float*)d_in[2];
    const float* r_b1    = (const float*)d_in[3];
    const float* r_w2    = (const float*)d_in[4];
    const float* r_b2    = (const float*)d_in[5];
    const float* r_w3    = (const float*)d_in[6];
    const float* r_b3    = (const float*)d_in[7];
    // d_in[8] = lstm_wih: multiplied by zero input in the reference -> unused
    const float* whh     = (const float*)d_in[9];
    const float* bih     = (const float*)d_in[10];
    const float* bhh     = (const float*)d_in[11];
    const float* proj_w  = (const float*)d_in[12];
    const float* proj_b  = (const float*)d_in[13];
    const float* w_w1    = (const float*)d_in[14];
    const float* w_b1    = (const float*)d_in[15];
    const float* w_w2    = (const float*)d_in[16];
    const float* w_b2    = (const float*)d_in[17];
    const float* w_w3    = (const float*)d_in[18];
    const float* w_b3    = (const float*)d_in[19];
    const float* empty_v = (const float*)d_in[20];
    float* outp = (float*)d_out;

    rpe_fused<<<NBATCH, 256, 0, stream>>>(
        input, lengths,
        r_w1, r_b1, r_w2, r_b2, r_w3, r_b3,
        whh, bih, bhh,
        proj_w, proj_b,
        w_w1, w_b1, w_w2, w_b2, w_w3, w_b3,
        empty_v, outp);
}

// Round 4
// 1280.817 us; speedup vs baseline: 1.5232x; 1.5232x over previous
//
#include <hip/hip_runtime.h>
#include <math.h>

#define NBATCH 4096
#define SS 512
#define EE 64
#define MM 16
#define HH 32
#define OUTD 64
#define NSTEPS 5
#define NTHR 256

__device__ __forceinline__ float fast_sigmoid(float x) {
    return 1.0f / (1.0f + __expf(-x));
}
__device__ __forceinline__ float fast_tanh(float x) {
    // tanh(x) = 1 - 2/(exp(2x)+1)
    return 1.0f - 2.0f / (__expf(2.0f * x) + 1.0f);
}

// Reading-block MLP for one row; result in registers.
//
// Anti-demotion discipline (the entire lesson of rounds 0-2):
//  * The neuron loops (j) are ROLLED (#pragma unroll 1) so each body is ~70
//    instructions — the inner k-loops then ALWAYS fully unroll and every
//    register-array index is a compile-time constant. (Fully unrolling the
//    whole MLP made clang's unroller bail, leaving dynamic indices that
//    demoted h1/h2/x to scratch: 700 MB of WRITE_SIZE at VGPR_Count=64.)
//  * The rolled j-loop's output h[j] (dynamic j) is parked in a PER-THREAD
//    LDS COLUMN scr[j*256+tid] (lane-consecutive -> 2 lanes/bank -> free),
//    then read back with constant indices into registers for the next layer.
//  * Weight addresses depend only on the uniform loop counter -> scalar
//    s_load path (SMEM pipe, parallel to VALU).
//  * x[64] is constant-indexed everywhere and live only across small rolled
//    loops: peak pressure ~85 VGPR < 128 budget -> no spill.
__device__ __forceinline__ void mlp_row(
    const float* __restrict__ xrow,
    const float* __restrict__ r_w1, const float* __restrict__ r_b1,
    const float* __restrict__ r_w2, const float* __restrict__ r_b2,
    const float* __restrict__ r_w3, const float* __restrict__ r_b3,
    float* __restrict__ scr, const int tid, float (&mout)[MM])
{
    float x[EE];
    {
        const float4* xp = reinterpret_cast<const float4*>(xrow);
        #pragma unroll
        for (int i = 0; i < EE / 4; ++i) {
            const float4 v = xp[i];
            x[4*i+0] = v.x; x[4*i+1] = v.y; x[4*i+2] = v.z; x[4*i+3] = v.w;
        }
    }

    // layer 1: 64 -> 32, relu
    #pragma unroll 1
    for (int j = 0; j < HH; ++j) {
        const float* w = r_w1 + j * EE;          // uniform -> s_load
        float a0 = 0.f, a1 = 0.f, a2 = 0.f, a3 = 0.f;
        #pragma unroll
        for (int k = 0; k < EE; k += 4) {
            a0 = fmaf(x[k+0], w[k+0], a0);
            a1 = fmaf(x[k+1], w[k+1], a1);
            a2 = fmaf(x[k+2], w[k+2], a2);
            a3 = fmaf(x[k+3], w[k+3], a3);
        }
        scr[j * NTHR + tid] = fmaxf((a0 + a1) + (a2 + a3) + r_b1[j], 0.0f);
    }
    float h1[HH];
    #pragma unroll
    for (int k = 0; k < HH; ++k) h1[k] = scr[k * NTHR + tid];

    // layer 2: 32 -> 32, relu
    #pragma unroll 1
    for (int j = 0; j < HH; ++j) {
        const float* w = r_w2 + j * HH;          // uniform -> s_load
        float a0 = 0.f, a1 = 0.f, a2 = 0.f, a3 = 0.f;
        #pragma unroll
        for (int k = 0; k < HH; k += 4) {
            a0 = fmaf(h1[k+0], w[k+0], a0);
            a1 = fmaf(h1[k+1], w[k+1], a1);
            a2 = fmaf(h1[k+2], w[k+2], a2);
            a3 = fmaf(h1[k+3], w[k+3], a3);
        }
        scr[j * NTHR + tid] = fmaxf((a0 + a1) + (a2 + a3) + r_b2[j], 0.0f);
    }
    float h2[HH];
    #pragma unroll
    for (int k = 0; k < HH; ++k) h2[k] = scr[k * NTHR + tid];

    // layer 3: 32 -> 16, linear
    #pragma unroll 1
    for (int d = 0; d < MM; ++d) {
        const float* w = r_w3 + d * HH;          // uniform -> s_load
        float a0 = 0.f, a1 = 0.f, a2 = 0.f, a3 = 0.f;
        #pragma unroll
        for (int k = 0; k < HH; k += 4) {
            a0 = fmaf(h2[k+0], w[k+0], a0);
            a1 = fmaf(h2[k+1], w[k+1], a1);
            a2 = fmaf(h2[k+2], w[k+2], a2);
            a3 = fmaf(h2[k+3], w[k+3], a3);
        }
        scr[d * NTHR + tid] = (a0 + a1) + (a2 + a3) + r_b3[d];
    }
    #pragma unroll
    for (int d = 0; d < MM; ++d) mout[d] = scr[d * NTHR + tid];
}

extern "C" __global__ void __launch_bounds__(256, 4)
rpe_fused(const float* __restrict__ input,
          const int* __restrict__ lengths,
          const float* __restrict__ r_w1, const float* __restrict__ r_b1,
          const float* __restrict__ r_w2, const float* __restrict__ r_b2,
          const float* __restrict__ r_w3, const float* __restrict__ r_b3,
          const float* __restrict__ lstm_whh,
          const float* __restrict__ lstm_bih, const float* __restrict__ lstm_bhh,
          const float* __restrict__ proj_w, const float* __restrict__ proj_b,
          const float* __restrict__ w_w1, const float* __restrict__ w_b1,
          const float* __restrict__ w_w2, const float* __restrict__ w_b2,
          const float* __restrict__ w_w3, const float* __restrict__ w_b3,
          const float* __restrict__ empty_vec,
          float* __restrict__ out)
{
    // 32 KB per-thread-column scratch for the MLP layer hand-offs.
    __shared__ float s_scr[HH * NTHR];
    // Phase-2 state (~1.3 KB).
    __shared__ float s_qstar[2 * MM];
    __shared__ float s_c[HH];
    __shared__ float s_h[HH];
    __shared__ float s_gates[4 * HH];
    __shared__ float s_q[MM];
    __shared__ float s_wmax[4];
    __shared__ float s_wsum[4];
    __shared__ float s_rpart[4 * MM];
    __shared__ float s_o1[HH];
    __shared__ float s_o2[HH];

    const int b    = blockIdx.x;
    const int tid  = threadIdx.x;
    const int lane = tid & 63;
    const int wid  = tid >> 6;

    const int len      = lengths[b];
    const int safe_len = len > 0 ? len : 1;

    if (tid < HH) { s_qstar[tid] = 0.0f; s_c[tid] = 0.0f; }

    // ---------------- Phase 1: memories, kept in registers ----------------
    // Row->thread mapping matches phase-2 attention (s1=tid, s2=tid+256).
    float m1[MM], m2[MM];
    mlp_row(input + ((size_t)b * SS + tid) * EE,
            r_w1, r_b1, r_w2, r_b2, r_w3, r_b3, s_scr, tid, m1);
    mlp_row(input + ((size_t)b * SS + tid + 256) * EE,
            r_w1, r_b1, r_w2, r_b2, r_w3, r_b3, s_scr, tid, m2);
    __syncthreads();   // covers the s_qstar/s_c init

    // ---------------- Phase 2: 5 process steps ----------------
    for (int step = 0; step < NSTEPS; ++step) {
        // gates = q_star @ whh.T + bih + bhh (zero input => no wih term)
        if (tid < 4 * HH) {
            float acc = lstm_bih[tid] + lstm_bhh[tid];
            #pragma unroll
            for (int k = 0; k < HH; ++k)
                acc = fmaf(lstm_whh[tid * HH + k], s_qstar[k], acc);
            s_gates[tid] = acc;
        }
        __syncthreads();
        if (tid < HH) {
            const float ig = fast_sigmoid(s_gates[tid]);
            const float fg = fast_sigmoid(s_gates[HH + tid]);
            const float gg = fast_tanh(s_gates[2 * HH + tid]);
            const float og = fast_sigmoid(s_gates[3 * HH + tid]);
            const float c  = fg * s_c[tid] + ig * gg;
            s_c[tid] = c;
            s_h[tid] = og * fast_tanh(c);
        }
        __syncthreads();
        // q = h @ proj_w.T + proj_b ; q_star[0:16] = q
        if (tid < MM) {
            float acc = proj_b[tid];
            #pragma unroll
            for (int k = 0; k < HH; ++k)
                acc = fmaf(proj_w[tid * HH + k], s_h[k], acc);
            s_q[tid] = acc;
            s_qstar[tid] = acc;
        }
        __syncthreads();

        // attention on register-resident memories
        float qreg[MM];
        #pragma unroll
        for (int d = 0; d < MM; ++d) qreg[d] = s_q[d];  // broadcast reads

        float e1 = 0.0f, e2 = 0.0f;
        #pragma unroll
        for (int d = 0; d < MM; ++d) {
            e1 = fmaf(m1[d], qreg[d], e1);
            e2 = fmaf(m2[d], qreg[d], e2);
        }
        if (tid       >= safe_len) e1 = -1e30f;
        if (tid + 256 >= safe_len) e2 = -1e30f;

        float mv = fmaxf(e1, e2);
        #pragma unroll
        for (int off = 32; off > 0; off >>= 1)
            mv = fmaxf(mv, __shfl_xor(mv, off, 64));
        if (lane == 0) s_wmax[wid] = mv;
        __syncthreads();
        const float maxv = fmaxf(fmaxf(s_wmax[0], s_wmax[1]),
                                 fmaxf(s_wmax[2], s_wmax[3]));

        const float p1 = __expf(e1 - maxv);   // masked -> exp(-huge) = 0
        const float p2 = __expf(e2 - maxv);
        float ds = p1 + p2;
        #pragma unroll
        for (int off = 32; off > 0; off >>= 1)
            ds += __shfl_xor(ds, off, 64);
        if (lane == 0) s_wsum[wid] = ds;

        float rv[MM];
        #pragma unroll
        for (int d = 0; d < MM; ++d) {
            float v = fmaf(p1, m1[d], p2 * m2[d]);
            #pragma unroll
            for (int off = 32; off > 0; off >>= 1)
                v += __shfl_xor(v, off, 64);
            rv[d] = v;
        }
        if (lane == 0) {
            #pragma unroll
            for (int d = 0; d < MM; ++d) s_rpart[wid * MM + d] = rv[d];
        }
        __syncthreads();
        if (tid < MM) {
            const float denom =
                s_wsum[0] + s_wsum[1] + s_wsum[2] + s_wsum[3];
            const float rval = (s_rpart[tid] + s_rpart[MM + tid] +
                                s_rpart[2 * MM + tid] + s_rpart[3 * MM + tid]) / denom;
            s_qstar[MM + tid] = rval;   // q_star[16:32] = r
        }
        __syncthreads();
    }

    // ---------------- Phase 3: write MLP + empty-set override ----------------
    if (tid < HH) {
        float acc = w_b1[tid];
        #pragma unroll
        for (int k = 0; k < 2 * MM; ++k)
            acc = fmaf(w_w1[tid * 2 * MM + k], s_qstar[k], acc);
        s_o1[tid] = fmaxf(acc, 0.0f);
    }
    __syncthreads();
    if (tid < HH) {
        float acc = w_b2[tid];
        #pragma unroll
        for (int k = 0; k < HH; ++k)
            acc = fmaf(w_w2[tid * HH + k], s_o1[k], acc);
        s_o2[tid] = fmaxf(acc, 0.0f);
    }
    __syncthreads();
    if (tid < OUTD) {
        float res;
        if (len > 0) {
            float acc = w_b3[tid];
            #pragma unroll
            for (int k = 0; k < HH; ++k)
                acc = fmaf(w_w3[tid * HH + k], s_o2[k], acc);
            res = acc;
        } else {
            res = empty_vec[tid];
        }
        out[(size_t)b * OUTD + tid] = res;
    }
}

extern "C" void kernel_launch(void* const* d_in, const int* in_sizes, int n_in,
                              void* d_out, int out_size, void* d_ws, size_t ws_size,
                              hipStream_t stream)
{
    const float* input   = (const float*)d_in[0];
    const int*   lengths = (const int*)  d_in[1];
    const float* r_w1    = (const float*)d_in[2];
    const float* r_b1    = (const float*)d_in[3];
    const float* r_w2    = (const float*)d_in[4];
    const float* r_b2    = (const float*)d_in[5];
    const float* r_w3    = (const float*)d_in[6];
    const float* r_b3    = (const float*)d_in[7];
    // d_in[8] = lstm_wih: multiplied by zero input in the reference -> unused
    const float* whh     = (const float*)d_in[9];
    const float* bih     = (const float*)d_in[10];
    const float* bhh     = (const float*)d_in[11];
    const float* proj_w  = (const float*)d_in[12];
    const float* proj_b  = (const float*)d_in[13];
    const float* w_w1    = (const float*)d_in[14];
    const float* w_b1    = (const float*)d_in[15];
    const float* w_w2    = (const float*)d_in[16];
    const float* w_b2    = (const float*)d_in[17];
    const float* w_w3    = (const float*)d_in[18];
    const float* w_b3    = (const float*)d_in[19];
    const float* empty_v = (const float*)d_in[20];
    float* outp = (float*)d_out;

    rpe_fused<<<NBATCH, 256, 0, stream>>>(
        input, lengths,
        r_w1, r_b1, r_w2, r_b2, r_w3, r_b3,
        whh, bih, bhh,
        proj_w, proj_b,
        w_w1, w_b1, w_w2, w_b2, w_w3, w_b3,
        empty_v, outp);
}